// Round 16
// baseline (2564.209 us; speedup 1.0000x reference)
//
#include <hip/hip_runtime.h>
#include <hip/hip_bf16.h>

// WaveOperator: Fourier-domain 3-term recurrence + per-row inverse FFT sampling.
// A_{t+1}(p,q) = (2-4*fil(p,q)) * A_t - A_{t-1};  y[b,j,t] = Re(ifft2(A_{t+1})[u_j,v_j])
// R16 = R15 with the reduce kernel FUSED into sim via atomicAdd (43 adds per output, device
// scope), 1/N^2 folded into the per-lane phase constants, and the partial buffer deleted.
// Ceiling note (R15 counters): sim's LDS pipe is ~80% busy at structurally-minimum bank
// patterns (SQ_LDS_BANK_CONFLICT = unavoidable multi-dword aliasing); all structural
// variants (R9/R11-R14) measured worse. This round only removes inter-kernel overhead.

#define NOUT 512
#define NB 16
#define NPHI 256
#define NT 240
#define RPB 6             // rows per block (= waves per block)
#define NGRP 43           // row groups: 43*6 = 258 = rows 0..257 (257 gets zero phase)

#define WREG 5184         // per-wave LDS region (T1 pitch 80 -> 5120; T2 pitch 528 aliased)

typedef float v2f __attribute__((ext_vector_type(2)));
typedef float v4f __attribute__((ext_vector_type(4)));

__device__ __forceinline__ v2f cmulv(v2f a, v2f b) {
    return v2f{fmaf(a.x, b.x, -a.y * b.y), fmaf(a.x, b.y, a.y * b.x)};
}
__device__ __forceinline__ v2f cmuliv(v2f a) { return v2f{-a.y, a.x}; }
__device__ __forceinline__ v2f cmulw8v(v2f a) {
    const float s = 0.70710678118654752f; return v2f{s * (a.x - a.y), s * (a.x + a.y)};
}
__device__ __forceinline__ v2f cmulw83v(v2f a) {
    const float s = 0.70710678118654752f; return v2f{-s * (a.x + a.y), s * (a.x - a.y)};
}

// 8-pt DFT, positive exponent: Y[k] = sum_r y[r] * exp(+2pi i rk/8)
__device__ __forceinline__ void dft8p(const v2f y[8], v2f Y[8]) {
    v2f t0 = y[0] + y[4], t4 = y[0] - y[4];
    v2f t1 = y[1] + y[5], t5 = cmulw8v(y[1] - y[5]);
    v2f t2 = y[2] + y[6], t6 = cmuliv(y[2] - y[6]);
    v2f t3 = y[3] + y[7], t7 = cmulw83v(y[3] - y[7]);
    v2f u0 = t0 + t2, u2 = t0 - t2;
    v2f u1 = t1 + t3, u3 = cmuliv(t1 - t3);
    Y[0] = u0 + u1; Y[4] = u0 - u1;
    Y[2] = u2 + u3; Y[6] = u2 - u3;
    v2f v0 = t4 + t6, v2 = t4 - t6;
    v2f v1 = t5 + t7, v3 = cmuliv(t5 - t7);
    Y[1] = v0 + v1; Y[5] = v0 - v1;
    Y[3] = v2 + v3; Y[7] = v2 - v3;
}

// W512^m from half-table
__device__ __forceinline__ v2f wlookup(const float2* trig, int m) {
    m &= 511;
    float2 ph = trig[m & 255];
    return (m & 256) ? v2f{-ph.x, -ph.y} : v2f{ph.x, ph.y};
}

// hot-loop step: wave-private 512-pt inverse DFT (8x8x8 four-step, aliased region), cross-wave
// sensor gather (barrier alpha: region reuse; barrier beta: T published), atomicAdd into out.
__device__ __forceinline__ void fft_sample(
    const v2f y[8], const v2f tA[8], const v2f tB[8],
    char* awBase, char* arBase, char* bwBase, char* brBase,
    const char* ldsBase, int spos, const v2f ph[RPB], bool active,
    float* oOut)
{
    v2f G[8];
    dft8p(y, G);
#pragma unroll
    for (int k1 = 1; k1 < 8; ++k1) G[k1] = cmulv(G[k1], tA[k1]);
    __syncthreads();   // barrier alpha: prior step's gathers done before region reuse
    *(v4f*)(awBase +  0) = v4f{G[0].x, G[0].y, G[1].x, G[1].y};
    *(v4f*)(awBase + 16) = v4f{G[2].x, G[2].y, G[3].x, G[3].y};
    *(v4f*)(awBase + 32) = v4f{G[4].x, G[4].y, G[5].x, G[5].y};
    *(v4f*)(awBase + 48) = v4f{G[6].x, G[6].y, G[7].x, G[7].y};
    v2f ga[8];
#pragma unroll
    for (int a2 = 0; a2 < 8; ++a2) ga[a2] = *(const v2f*)(arBase + a2 * 640);
    v2f H[8];
    dft8p(ga, H);
#pragma unroll
    for (int m1 = 1; m1 < 8; ++m1) H[m1] = cmulv(H[m1], tB[m1]);
    *(v4f*)(bwBase +  0) = v4f{H[0].x, H[0].y, H[1].x, H[1].y};
    *(v4f*)(bwBase + 16) = v4f{H[2].x, H[2].y, H[3].x, H[3].y};
    *(v4f*)(bwBase + 32) = v4f{H[4].x, H[4].y, H[5].x, H[5].y};
    *(v4f*)(bwBase + 48) = v4f{H[6].x, H[6].y, H[7].x, H[7].y};
    v2f hc[8];
#pragma unroll
    for (int c2 = 0; c2 < 8; ++c2) hc[c2] = *(const v2f*)(brBase + c2 * 64);
    v2f X[8];
    dft8p(hc, X);
    *(v4f*)(awBase +  0) = v4f{X[0].x, X[0].y, X[1].x, X[1].y};
    *(v4f*)(awBase + 16) = v4f{X[2].x, X[2].y, X[3].x, X[3].y};
    *(v4f*)(awBase + 32) = v4f{X[4].x, X[4].y, X[5].x, X[5].y};
    *(v4f*)(awBase + 48) = v4f{X[6].x, X[6].y, X[7].x, X[7].y};
    __syncthreads();   // barrier beta: all waves' T ready
    if (active) {
        float acc = 0.0f;
#pragma unroll
        for (int ww = 0; ww < RPB; ++ww) {
            v2f q = *(const v2f*)(ldsBase + ww * WREG + spos);
            acc = fmaf(q.x, ph[ww].x, fmaf(-q.y, ph[ww].y, acc));
        }
        atomicAdd(oOut, acc);   // 43 row-group contributions per output element
    }
}

// ---------------- init kernels (run once, shuffle FFT) -------------------------------------------
__device__ __forceinline__ void cbfly(float& ar, float& ai, float& br, float& bi,
                                      float wr, float wi) {
    float dr = ar - br, di = ai - bi;
    ar = ar + br; ai = ai + bi;
    br = fmaf(dr, wr, -di * wi);
    bi = fmaf(dr, wi,  di * wr);
}

__device__ __forceinline__ void init_trig(float2* trig, int tid) {
    if (tid < 256) {
        float ang = (float)tid * (6.283185307179586f / 512.0f);
        float s, c;
        sincosf(ang, &s, &c);
        trig[tid] = make_float2(c, s);
    }
}

__device__ __forceinline__ void fft512_inv_lds(float* xr, float* xi, const float2* trig, int L) {
#pragma unroll
    for (int r = 0; r < 4; ++r) {
        float2 w = trig[(r << 6) + L];
        cbfly(xr[r], xi[r], xr[r + 4], xi[r + 4], w.x, w.y);
    }
    {
        float2 w0 = trig[L << 1];
        float2 w1 = trig[(64 + L) << 1];
        cbfly(xr[0], xi[0], xr[2], xi[2], w0.x, w0.y);
        cbfly(xr[1], xi[1], xr[3], xi[3], w1.x, w1.y);
        cbfly(xr[4], xi[4], xr[6], xi[6], w0.x, w0.y);
        cbfly(xr[5], xi[5], xr[7], xi[7], w1.x, w1.y);
    }
    {
        float2 w = trig[L << 2];
        cbfly(xr[0], xi[0], xr[1], xi[1], w.x, w.y);
        cbfly(xr[2], xi[2], xr[3], xi[3], w.x, w.y);
        cbfly(xr[4], xi[4], xr[5], xi[5], w.x, w.y);
        cbfly(xr[6], xi[6], xr[7], xi[7], w.x, w.y);
    }
#pragma unroll
    for (int s = 3; s <= 8; ++s) {
        const int half = 512 >> (s + 1);
        const int ex = (L & (half - 1)) << s;
        float2 w = trig[ex];
        const bool hi = (L & half) != 0;
        float wr = hi ? w.x : 1.0f;
        float wi = hi ? w.y : 0.0f;
        float sg = hi ? -1.0f : 1.0f;
#pragma unroll
        for (int r = 0; r < 8; ++r) {
            float orv = __shfl_xor(xr[r], half);
            float oiv = __shfl_xor(xi[r], half);
            float tr = fmaf(sg, xr[r], orv);
            float ti = fmaf(sg, xi[r], oiv);
            xr[r] = fmaf(tr, wr, -ti * wi);
            xi[r] = fmaf(tr, wi,  ti * wr);
        }
    }
}

__global__ __launch_bounds__(256) void f1_kernel(const float* __restrict__ f,
                                                 float2* __restrict__ R) {
    __shared__ float2 trig[256];
    const int tid = threadIdx.x;
    init_trig(trig, tid);
    __syncthreads();
    const int w = tid >> 6, L = tid & 63;
    const int x = 128 + blockIdx.x * 4 + w;   // nonzero rows only: [128, 384)
    const int b = blockIdx.y;
    const float* frow = f + ((size_t)b * 256 + (x - 128)) * 256;
    float xr[8], xi[8];
#pragma unroll
    for (int r = 0; r < 8; ++r) {
        int e = r * 64 + L;
        xr[r] = (e >= 128 && e < 384) ? frow[e - 128] : 0.0f;
        xi[r] = 0.0f;
    }
    fft512_inv_lds(xr, xi, trig, L);
    float2* Rrow = R + ((size_t)b * NOUT + x) * NOUT;
#pragma unroll
    for (int r = 0; r < 8; ++r) {
        int e = r * 64 + L;
        int k = __brev((unsigned)e) >> 23;
        Rrow[k] = make_float2(xr[r], -xi[r]);
    }
}

// f2: rows x outside [128,384) of R were never written — treat as 0 (e = r*64+L in range iff r in [2,6)).
__global__ __launch_bounds__(256) void f2_kernel(const float2* __restrict__ R,
                                                 float2* __restrict__ A0) {
    __shared__ float2 trig[256];
    const int tid = threadIdx.x;
    init_trig(trig, tid);
    __syncthreads();
    const int w = tid >> 6, L = tid & 63;
    const int q = blockIdx.x * 4 + w;
    const int b = blockIdx.y;
    float xr[8], xi[8];
#pragma unroll
    for (int r = 0; r < 8; ++r) {
        if (r >= 2 && r < 6) {
            int e = r * 64 + L;
            float2 v = R[((size_t)b * NOUT + e) * NOUT + q];
            xr[r] = v.x;
            xi[r] = -v.y;
        } else {
            xr[r] = 0.0f;
            xi[r] = 0.0f;
        }
    }
    fft512_inv_lds(xr, xi, trig, L);
#pragma unroll
    for (int r = 0; r < 8; ++r) {
        int e = r * 64 + L;
        int p = __brev((unsigned)e) >> 23;
        A0[((size_t)b * NOUT + p) * NOUT + q] = make_float2(xr[r], -xi[r]);
    }
}

// ---------------- simulation: single dispatch, all 240 steps, fused output accumulation ----------
// block = (row group g of RPB rows, batch b); wave w owns row p = RPB*g + w, p in 0..257.
// Threads 0..255 each own one sensor; per step they sum the block's RPB rows and atomicAdd
// into out (1/N^2 pre-folded into the phase constants). No state writeback (single chunk).
__global__ __launch_bounds__(384, 4) void sim_kernel(
    const float* __restrict__ fil,
    const int* __restrict__ idx0, const int* __restrict__ idx1,
    const float2* __restrict__ A0,
    float* __restrict__ out)
{
    __shared__ __align__(16) char waveMem[RPB * WREG];   // 31104 B
    __shared__ float2 trig[256];                         //  2048 B -> 33152 B total

    const int tid = threadIdx.x;              // 0..383
    const int w = tid >> 6, L = tid & 63;
    const int g = blockIdx.x, b = blockIdx.y;
    const int p = g * RPB + w;                // 0..257
    const int k1L = L >> 3, cL = L & 7;
    const float invN2 = 1.0f / (512.0f * 512.0f);

    if (tid < 256) {
        float ang = (float)tid * (6.283185307179586f / 512.0f);
        float s, c;
        sincosf(ang, &s, &c);
        trig[tid] = make_float2(c, s);
    }
    __syncthreads();

    // --- per-lane constant twiddles ---
    v2f tA[8], tB[8];
#pragma unroll
    for (int k1 = 1; k1 < 8; ++k1) tA[k1] = wlookup(trig, L * k1);
#pragma unroll
    for (int m1 = 1; m1 < 8; ++m1) tB[m1] = wlookup(trig, 8 * cL * m1);

    // --- sensor constants: thread tid<256 owns sensor j=tid; scale folded in ---
    const bool active = tid < 256;
    int spos = 0;
    v2f ph[RPB];
    if (active) {
        int u = idx0[tid];
        int v = idx1[tid];
        spos = ((v & 7) * 8 + ((v >> 3) & 7)) * 80 + (v >> 6) * 8;
        // Hermitian fold phase x 1/N^2: p==0 -> s, p==256 -> (-1)^u s, p==257 -> 0, else 2s*W512^{pu}
#pragma unroll
        for (int ww = 0; ww < RPB; ++ww) {
            int prow = g * RPB + ww;
            v2f a0;
            if (prow == 0)        a0 = v2f{invN2, 0.0f};
            else if (prow == 256) a0 = v2f{(u & 1) ? -invN2 : invN2, 0.0f};
            else if (prow == 257) a0 = v2f{0.0f, 0.0f};
            else                  a0 = (2.0f * invN2) * wlookup(trig, prow * u);
            ph[ww] = a0;
        }
    } else {
#pragma unroll
        for (int ww = 0; ww < RPB; ++ww) ph[ww] = v2f{0.0f, 0.0f};
    }

    // --- per-lane LDS bases (immediate-offset addressing inside the loop) ---
    char* myA    = waveMem + w * WREG;
    char* awBase = myA + L * 80;                 // T1 write / final T write (pitch 80)
    char* arBase = myA + cL * 80 + k1L * 8;      // T1 read (offsets a*640)
    char* bwBase = myA + k1L * 528 + cL * 64;    // T2 write (aliases T1 region; in-order DS)
    char* brBase = myA + k1L * 528 + cL * 8;     // T2 read (offsets c*64)

    // --- load state + filter into registers ---
    v2f a[8], bb[8];
    float C[8];
    {
        const size_t rowBase = ((size_t)b * NOUT + p) * NOUT;
        const float* filRow = fil + (size_t)p * NOUT;
#pragma unroll
        for (int r = 0; r < 8; ++r) {
            int e = r * 64 + L;
            float2 a0 = A0[rowBase + e];
            a[r] = v2f{a0.x, a0.y};
            bb[r] = a[r];                        // A_{-1} = A_0
            C[r] = fmaf(-4.0f, filRow[e], 2.0f);
        }
    }

    float* oOut = out + ((size_t)b * NPHI + (tid & (NPHI - 1))) * NT;

    for (int tl = 0; tl < NT; tl += 2) {
        // step A: bb becomes A_{t+1}
#pragma unroll
        for (int r = 0; r < 8; ++r) bb[r] = v2f{C[r], C[r]} * a[r] - bb[r];
        fft_sample(bb, tA, tB, awBase, arBase, bwBase, brBase,
                   waveMem, spos, ph, active, oOut + tl);
        // step B: a becomes A_{t+2}
#pragma unroll
        for (int r = 0; r < 8; ++r) a[r] = v2f{C[r], C[r]} * bb[r] - a[r];
        fft_sample(a, tA, tB, awBase, arBase, bwBase, brBase,
                   waveMem, spos, ph, active, oOut + tl + 1);
    }
}

extern "C" void kernel_launch(void* const* d_in, const int* in_sizes, int n_in,
                              void* d_out, int out_size, void* d_ws, size_t ws_size,
                              hipStream_t stream) {
    (void)in_sizes; (void)n_in; (void)ws_size;
    const float* f   = (const float*)d_in[0];   // [16,1,256,256]
    const float* fil = (const float*)d_in[1];   // [512,512]
    const int* idx0  = (const int*)d_in[2];     // [256]
    const int* idx1  = (const int*)d_in[3];     // [256]
    float* out = (float*)d_out;                 // [16,1,256,240]

    char* ws = (char*)d_ws;
    const size_t stateBytes = (size_t)NB * NOUT * NOUT * sizeof(float2);  // 33.55 MB
    float2* A0       = (float2*)ws;
    float2* Rscratch = (float2*)(ws + stateBytes);

    // out accumulates 43 atomic contributions per element -> must start at zero
    hipMemsetAsync(out, 0, (size_t)out_size * sizeof(float), stream);

    // no R memset: f1 writes rows [128,384); f2 skips the rest as known-zero
    f1_kernel<<<dim3(64, NB), 256, 0, stream>>>(f, Rscratch);
    f2_kernel<<<dim3(128, NB), 256, 0, stream>>>(Rscratch, A0);
    sim_kernel<<<dim3(NGRP, NB), RPB * 64, 0, stream>>>(fil, idx0, idx1, A0, out);
}

// Round 17
// 990.307 us; speedup vs baseline: 2.5893x; 2.5893x over previous
//
#include <hip/hip_runtime.h>
#include <hip/hip_bf16.h>

// WaveOperator: Fourier-domain 3-term recurrence + per-row inverse FFT sampling.
// A_{t+1}(p,q) = (2-4*fil(p,q)) * A_t - A_{t-1};  y[b,j,t] = Re(ifft2(A_{t+1})[u_j,v_j])
// R17 = R15 verbatim (measured best: 993.6 us). R16's atomicAdd output fusion regressed 2.6x
// (42M device-scope atomics -> 1.32 GB RMW traffic); the streaming reduce kernel stands.
// Ceiling evidence: sim (94% of runtime) is ~80% LDS-pipe busy at structurally-minimum bank
// patterns; all structural variants measured worse (R9/R11/R12/R13/R14/R16). Parallelism is
// capped at 4128 waves (row = min FFT unit); 18 waves/CU critical split is distribution-optimal.

#define NOUT 512
#define NB 16
#define NPHI 256
#define NT 240
#define RPB 6             // rows per block (= waves per block)
#define NGRP 43           // row groups: 43*6 = 258 = rows 0..257 (257 gets zero phase)

#define WREG 5184         // per-wave LDS region (T1 pitch 80 -> 5120; T2 pitch 528 aliased)

typedef float v2f __attribute__((ext_vector_type(2)));
typedef float v4f __attribute__((ext_vector_type(4)));

__device__ __forceinline__ v2f cmulv(v2f a, v2f b) {
    return v2f{fmaf(a.x, b.x, -a.y * b.y), fmaf(a.x, b.y, a.y * b.x)};
}
__device__ __forceinline__ v2f cmuliv(v2f a) { return v2f{-a.y, a.x}; }
__device__ __forceinline__ v2f cmulw8v(v2f a) {
    const float s = 0.70710678118654752f; return v2f{s * (a.x - a.y), s * (a.x + a.y)};
}
__device__ __forceinline__ v2f cmulw83v(v2f a) {
    const float s = 0.70710678118654752f; return v2f{-s * (a.x + a.y), s * (a.x - a.y)};
}

// 8-pt DFT, positive exponent: Y[k] = sum_r y[r] * exp(+2pi i rk/8)
__device__ __forceinline__ void dft8p(const v2f y[8], v2f Y[8]) {
    v2f t0 = y[0] + y[4], t4 = y[0] - y[4];
    v2f t1 = y[1] + y[5], t5 = cmulw8v(y[1] - y[5]);
    v2f t2 = y[2] + y[6], t6 = cmuliv(y[2] - y[6]);
    v2f t3 = y[3] + y[7], t7 = cmulw83v(y[3] - y[7]);
    v2f u0 = t0 + t2, u2 = t0 - t2;
    v2f u1 = t1 + t3, u3 = cmuliv(t1 - t3);
    Y[0] = u0 + u1; Y[4] = u0 - u1;
    Y[2] = u2 + u3; Y[6] = u2 - u3;
    v2f v0 = t4 + t6, v2 = t4 - t6;
    v2f v1 = t5 + t7, v3 = cmuliv(t5 - t7);
    Y[1] = v0 + v1; Y[5] = v0 - v1;
    Y[3] = v2 + v3; Y[7] = v2 - v3;
}

// W512^m from half-table
__device__ __forceinline__ v2f wlookup(const float2* trig, int m) {
    m &= 511;
    float2 ph = trig[m & 255];
    return (m & 256) ? v2f{-ph.x, -ph.y} : v2f{ph.x, ph.y};
}

// hot-loop step: wave-private 512-pt inverse DFT (8x8x8 four-step, aliased region), then the
// cross-wave sample: barrier alpha guards region reuse, barrier beta publishes T.
__device__ __forceinline__ void fft_sample(
    const v2f y[8], const v2f tA[8], const v2f tB[8],
    char* awBase, char* arBase, char* bwBase, char* brBase,
    const char* ldsBase, int spos, const v2f ph[RPB], bool active,
    float* pA)
{
    v2f G[8];
    dft8p(y, G);
#pragma unroll
    for (int k1 = 1; k1 < 8; ++k1) G[k1] = cmulv(G[k1], tA[k1]);
    __syncthreads();   // barrier alpha: prior step's gathers done before region reuse
    *(v4f*)(awBase +  0) = v4f{G[0].x, G[0].y, G[1].x, G[1].y};
    *(v4f*)(awBase + 16) = v4f{G[2].x, G[2].y, G[3].x, G[3].y};
    *(v4f*)(awBase + 32) = v4f{G[4].x, G[4].y, G[5].x, G[5].y};
    *(v4f*)(awBase + 48) = v4f{G[6].x, G[6].y, G[7].x, G[7].y};
    v2f ga[8];
#pragma unroll
    for (int a2 = 0; a2 < 8; ++a2) ga[a2] = *(const v2f*)(arBase + a2 * 640);
    v2f H[8];
    dft8p(ga, H);
#pragma unroll
    for (int m1 = 1; m1 < 8; ++m1) H[m1] = cmulv(H[m1], tB[m1]);
    *(v4f*)(bwBase +  0) = v4f{H[0].x, H[0].y, H[1].x, H[1].y};
    *(v4f*)(bwBase + 16) = v4f{H[2].x, H[2].y, H[3].x, H[3].y};
    *(v4f*)(bwBase + 32) = v4f{H[4].x, H[4].y, H[5].x, H[5].y};
    *(v4f*)(bwBase + 48) = v4f{H[6].x, H[6].y, H[7].x, H[7].y};
    v2f hc[8];
#pragma unroll
    for (int c2 = 0; c2 < 8; ++c2) hc[c2] = *(const v2f*)(brBase + c2 * 64);
    v2f X[8];
    dft8p(hc, X);
    *(v4f*)(awBase +  0) = v4f{X[0].x, X[0].y, X[1].x, X[1].y};
    *(v4f*)(awBase + 16) = v4f{X[2].x, X[2].y, X[3].x, X[3].y};
    *(v4f*)(awBase + 32) = v4f{X[4].x, X[4].y, X[5].x, X[5].y};
    *(v4f*)(awBase + 48) = v4f{X[6].x, X[6].y, X[7].x, X[7].y};
    __syncthreads();   // barrier beta: all waves' T ready
    if (active) {
        float acc = 0.0f;
#pragma unroll
        for (int ww = 0; ww < RPB; ++ww) {
            v2f q = *(const v2f*)(ldsBase + ww * WREG + spos);
            acc = fmaf(q.x, ph[ww].x, fmaf(-q.y, ph[ww].y, acc));
        }
        pA[0] = acc;
    }
}

// ---------------- init kernels (run once, shuffle FFT) -------------------------------------------
__device__ __forceinline__ void cbfly(float& ar, float& ai, float& br, float& bi,
                                      float wr, float wi) {
    float dr = ar - br, di = ai - bi;
    ar = ar + br; ai = ai + bi;
    br = fmaf(dr, wr, -di * wi);
    bi = fmaf(dr, wi,  di * wr);
}

__device__ __forceinline__ void init_trig(float2* trig, int tid) {
    if (tid < 256) {
        float ang = (float)tid * (6.283185307179586f / 512.0f);
        float s, c;
        sincosf(ang, &s, &c);
        trig[tid] = make_float2(c, s);
    }
}

__device__ __forceinline__ void fft512_inv_lds(float* xr, float* xi, const float2* trig, int L) {
#pragma unroll
    for (int r = 0; r < 4; ++r) {
        float2 w = trig[(r << 6) + L];
        cbfly(xr[r], xi[r], xr[r + 4], xi[r + 4], w.x, w.y);
    }
    {
        float2 w0 = trig[L << 1];
        float2 w1 = trig[(64 + L) << 1];
        cbfly(xr[0], xi[0], xr[2], xi[2], w0.x, w0.y);
        cbfly(xr[1], xi[1], xr[3], xi[3], w1.x, w1.y);
        cbfly(xr[4], xi[4], xr[6], xi[6], w0.x, w0.y);
        cbfly(xr[5], xi[5], xr[7], xi[7], w1.x, w1.y);
    }
    {
        float2 w = trig[L << 2];
        cbfly(xr[0], xi[0], xr[1], xi[1], w.x, w.y);
        cbfly(xr[2], xi[2], xr[3], xi[3], w.x, w.y);
        cbfly(xr[4], xi[4], xr[5], xi[5], w.x, w.y);
        cbfly(xr[6], xi[6], xr[7], xi[7], w.x, w.y);
    }
#pragma unroll
    for (int s = 3; s <= 8; ++s) {
        const int half = 512 >> (s + 1);
        const int ex = (L & (half - 1)) << s;
        float2 w = trig[ex];
        const bool hi = (L & half) != 0;
        float wr = hi ? w.x : 1.0f;
        float wi = hi ? w.y : 0.0f;
        float sg = hi ? -1.0f : 1.0f;
#pragma unroll
        for (int r = 0; r < 8; ++r) {
            float orv = __shfl_xor(xr[r], half);
            float oiv = __shfl_xor(xi[r], half);
            float tr = fmaf(sg, xr[r], orv);
            float ti = fmaf(sg, xi[r], oiv);
            xr[r] = fmaf(tr, wr, -ti * wi);
            xi[r] = fmaf(tr, wi,  ti * wr);
        }
    }
}

__global__ __launch_bounds__(256) void f1_kernel(const float* __restrict__ f,
                                                 float2* __restrict__ R) {
    __shared__ float2 trig[256];
    const int tid = threadIdx.x;
    init_trig(trig, tid);
    __syncthreads();
    const int w = tid >> 6, L = tid & 63;
    const int x = 128 + blockIdx.x * 4 + w;   // nonzero rows only: [128, 384)
    const int b = blockIdx.y;
    const float* frow = f + ((size_t)b * 256 + (x - 128)) * 256;
    float xr[8], xi[8];
#pragma unroll
    for (int r = 0; r < 8; ++r) {
        int e = r * 64 + L;
        xr[r] = (e >= 128 && e < 384) ? frow[e - 128] : 0.0f;
        xi[r] = 0.0f;
    }
    fft512_inv_lds(xr, xi, trig, L);
    float2* Rrow = R + ((size_t)b * NOUT + x) * NOUT;
#pragma unroll
    for (int r = 0; r < 8; ++r) {
        int e = r * 64 + L;
        int k = __brev((unsigned)e) >> 23;
        Rrow[k] = make_float2(xr[r], -xi[r]);
    }
}

// f2: rows x outside [128,384) of R were never written (and are not zeroed) — treat as 0.
// e = r*64 + L is in [128,384) exactly for r in [2,6).
__global__ __launch_bounds__(256) void f2_kernel(const float2* __restrict__ R,
                                                 float2* __restrict__ A0) {
    __shared__ float2 trig[256];
    const int tid = threadIdx.x;
    init_trig(trig, tid);
    __syncthreads();
    const int w = tid >> 6, L = tid & 63;
    const int q = blockIdx.x * 4 + w;
    const int b = blockIdx.y;
    float xr[8], xi[8];
#pragma unroll
    for (int r = 0; r < 8; ++r) {
        if (r >= 2 && r < 6) {
            int e = r * 64 + L;
            float2 v = R[((size_t)b * NOUT + e) * NOUT + q];
            xr[r] = v.x;
            xi[r] = -v.y;
        } else {
            xr[r] = 0.0f;
            xi[r] = 0.0f;
        }
    }
    fft512_inv_lds(xr, xi, trig, L);
#pragma unroll
    for (int r = 0; r < 8; ++r) {
        int e = r * 64 + L;
        int p = __brev((unsigned)e) >> 23;
        A0[((size_t)b * NOUT + p) * NOUT + q] = make_float2(xr[r], -xi[r]);
    }
}

// ---------------- time-chunk simulation ----------------------------------------------------------
// block = (row group g of RPB rows, batch b); wave w owns row p = RPB*g + w, p in 0..257.
// Threads 0..255 each own one sensor, summing the block's RPB rows after barrier beta.
__global__ __launch_bounds__(384, 4) void sim_kernel(
    const float* __restrict__ fil,
    const int* __restrict__ idx0, const int* __restrict__ idx1,
    float2* __restrict__ stateCur, float2* __restrict__ statePrev,
    float* __restrict__ partial, int Tc, int firstChunk, int lastChunk)
{
    __shared__ __align__(16) char waveMem[RPB * WREG];   // 31104 B
    __shared__ float2 trig[256];                         //  2048 B -> 33152 B total

    const int tid = threadIdx.x;              // 0..383
    const int w = tid >> 6, L = tid & 63;
    const int g = blockIdx.x, b = blockIdx.y;
    const int p = g * RPB + w;                // 0..257
    const int k1L = L >> 3, cL = L & 7;

    if (tid < 256) {
        float ang = (float)tid * (6.283185307179586f / 512.0f);
        float s, c;
        sincosf(ang, &s, &c);
        trig[tid] = make_float2(c, s);
    }
    __syncthreads();

    // --- per-lane constant twiddles ---
    v2f tA[8], tB[8];
#pragma unroll
    for (int k1 = 1; k1 < 8; ++k1) tA[k1] = wlookup(trig, L * k1);
#pragma unroll
    for (int m1 = 1; m1 < 8; ++m1) tB[m1] = wlookup(trig, 8 * cL * m1);

    // --- sensor constants: thread tid<256 owns sensor j=tid ---
    const bool active = tid < 256;
    int spos = 0;
    v2f ph[RPB];
    if (active) {
        int u = idx0[tid];
        int v = idx1[tid];
        spos = ((v & 7) * 8 + ((v >> 3) & 7)) * 80 + (v >> 6) * 8;
        // Hermitian fold phase: p==0 -> 1, p==256 -> (-1)^u, p==257 -> 0, else 2*W512^{pu}
#pragma unroll
        for (int ww = 0; ww < RPB; ++ww) {
            int prow = g * RPB + ww;
            v2f a0;
            if (prow == 0)        a0 = v2f{1.0f, 0.0f};
            else if (prow == 256) a0 = v2f{(u & 1) ? -1.0f : 1.0f, 0.0f};
            else if (prow == 257) a0 = v2f{0.0f, 0.0f};
            else                  a0 = 2.0f * wlookup(trig, prow * u);
            ph[ww] = a0;
        }
    } else {
#pragma unroll
        for (int ww = 0; ww < RPB; ++ww) ph[ww] = v2f{0.0f, 0.0f};
    }

    // --- per-lane LDS bases (immediate-offset addressing inside the loop) ---
    char* myA    = waveMem + w * WREG;
    char* awBase = myA + L * 80;                 // T1 write / final T write (pitch 80)
    char* arBase = myA + cL * 80 + k1L * 8;      // T1 read (offsets a*640)
    char* bwBase = myA + k1L * 528 + cL * 64;    // T2 write (aliases T1 region; in-order DS)
    char* brBase = myA + k1L * 528 + cL * 8;     // T2 read (offsets c*64)

    // --- load state + filter into registers ---
    v2f a[8], bb[8];
    float C[8];
    {
        const size_t rowBase = ((size_t)b * NOUT + p) * NOUT;
        const float* filRow = fil + (size_t)p * NOUT;
#pragma unroll
        for (int r = 0; r < 8; ++r) {
            int e = r * 64 + L;
            float2 a0 = stateCur[rowBase + e];
            a[r] = v2f{a0.x, a0.y};
            if (firstChunk) {
                bb[r] = a[r];
            } else {
                float2 a1 = statePrev[rowBase + e];
                bb[r] = v2f{a1.x, a1.y};
            }
            C[r] = fmaf(-4.0f, filRow[e], 2.0f);
        }
    }

    float* pOut = partial + ((size_t)g * Tc * NB + b) * NPHI + tid;

    for (int tl = 0; tl < Tc; tl += 2) {
        // step A: bb becomes A_{t+1}
#pragma unroll
        for (int r = 0; r < 8; ++r) bb[r] = v2f{C[r], C[r]} * a[r] - bb[r];
        fft_sample(bb, tA, tB, awBase, arBase, bwBase, brBase,
                   waveMem, spos, ph, active, pOut);
        pOut += NB * NPHI;
        // step B: a becomes A_{t+2}
#pragma unroll
        for (int r = 0; r < 8; ++r) a[r] = v2f{C[r], C[r]} * bb[r] - a[r];
        fft_sample(a, tA, tB, awBase, arBase, bwBase, brBase,
                   waveMem, spos, ph, active, pOut);
        pOut += NB * NPHI;
    }

    // --- save state for the next chunk (skipped when this is the last chunk) ---
    if (!lastChunk) {
        const size_t rowBase = ((size_t)b * NOUT + p) * NOUT;
#pragma unroll
        for (int r = 0; r < 8; ++r) {
            int e = r * 64 + L;
            stateCur[rowBase + e]  = make_float2(a[r].x, a[r].y);
            statePrev[rowBase + e] = make_float2(bb[r].x, bb[r].y);
        }
    }
}

// ---------------- reduce NGRP row-group partials -> out[b][j][t] ----------------------------------
__global__ __launch_bounds__(256) void reduce_kernel(const float* __restrict__ partial,
                                                     float* __restrict__ out,
                                                     int Tc, int tStart) {
    int id = blockIdx.x * 256 + threadIdx.x;   // over Tc*16*256, exact
    int j = id & 255;
    int b = (id >> 8) & 15;
    int tl = id >> 12;
    float s = 0.0f;
#pragma unroll
    for (int gg = 0; gg < NGRP; ++gg)
        s += partial[(((size_t)gg * Tc + tl) * NB + b) * NPHI + j];
    out[((size_t)b * NPHI + j) * NT + (tStart + tl)] = s * (1.0f / (512.0f * 512.0f));
}

extern "C" void kernel_launch(void* const* d_in, const int* in_sizes, int n_in,
                              void* d_out, int out_size, void* d_ws, size_t ws_size,
                              hipStream_t stream) {
    (void)in_sizes; (void)n_in; (void)out_size;
    const float* f   = (const float*)d_in[0];   // [16,1,256,256]
    const float* fil = (const float*)d_in[1];   // [512,512]
    const int* idx0  = (const int*)d_in[2];     // [256]
    const int* idx1  = (const int*)d_in[3];     // [256]
    float* out = (float*)d_out;                 // [16,1,256,240]

    char* ws = (char*)d_ws;
    const size_t stateBytes = (size_t)NB * NOUT * NOUT * sizeof(float2);  // 33.55 MB
    float2* stateCur  = (float2*)ws;
    float2* statePrev = (float2*)(ws + stateBytes);   // also reused as R scratch for f1/f2
    float*  partial   = (float*)(ws + 2 * stateBytes);
    size_t remain = (ws_size > 2 * stateBytes) ? ws_size - 2 * stateBytes : 0;

    // largest even time chunk whose partial buffer fits (even: the sim loop is 2-step unrolled)
    static const int tcs[] = {240, 120, 80, 60, 48, 40, 30, 24, 20, 16, 12, 10, 8, 6, 4, 2};
    int Tc = 2;
    for (int i = 0; i < 16; ++i) {
        size_t need = (size_t)NGRP * tcs[i] * NB * NPHI * sizeof(float);
        if (need <= remain) { Tc = tcs[i]; break; }
    }

    // no memset: f1 writes rows [128,384) of the R scratch; f2 skips the rest as known-zero
    f1_kernel<<<dim3(64, NB), 256, 0, stream>>>(f, statePrev);        // rows x in [128,384)
    f2_kernel<<<dim3(128, NB), 256, 0, stream>>>(statePrev, stateCur);
    for (int t0 = 0; t0 < NT; t0 += Tc) {
        int last = (t0 + Tc) >= NT ? 1 : 0;
        sim_kernel<<<dim3(NGRP, NB), RPB * 64, 0, stream>>>(fil, idx0, idx1, stateCur, statePrev,
                                                            partial, Tc, t0 == 0 ? 1 : 0, last);
        reduce_kernel<<<dim3(Tc * NB), 256, 0, stream>>>(partial, out, Tc, t0);
    }
}